// Round 7
// baseline (194.178 us; speedup 1.0000x reference)
//
#include <hip/hip_runtime.h>

#define BATCH        16384
#define SEQ          500
#define NUM_BUCKETS  4000000
#define NUM_FIELDS   63
#define NUM_SEGMENTS 64
#define BLOCK        256
#define ROWS_PER_BLK 4          // one wave per batch row

typedef int         int4v   __attribute__((ext_vector_type(4)));
typedef float       float4v __attribute__((ext_vector_type(4)));
typedef signed char schar;
typedef schar       char4v  __attribute__((ext_vector_type(4)));

#define N_VEC4 (NUM_BUCKETS / 4)   // 1,000,000 float4 groups

// d_ws layout: [0 .. 4M) int8 table | [4M .. 4M+4) absmax bits (int)
#define SCALE_OFF NUM_BUCKETS

// ---- k1: absmax over the fp32 table
__global__ __launch_bounds__(BLOCK) void reduce_absmax(
    const float4v* __restrict__ src, int* __restrict__ scale_bits)
{
    __shared__ float red[BLOCK / 64];
    float m = 0.0f;
    for (int i = blockIdx.x * BLOCK + threadIdx.x; i < N_VEC4; i += gridDim.x * BLOCK) {
        float4v v = __builtin_nontemporal_load(&src[i]);
        #pragma unroll
        for (int j = 0; j < 4; ++j) m = fmaxf(m, fabsf(v[j]));
    }
    #pragma unroll
    for (int off = 32; off >= 1; off >>= 1)
        m = fmaxf(m, __shfl_down(m, off, 64));
    if ((threadIdx.x & 63) == 0) red[threadIdx.x >> 6] = m;
    __syncthreads();
    if (threadIdx.x == 0) {
        float bm = red[0];
        #pragma unroll
        for (int w = 1; w < BLOCK / 64; ++w) bm = fmaxf(bm, red[w]);
        atomicMax(scale_bits, __float_as_int(bm));
    }
}

// ---- k2: fp32 -> int8 symmetric quantization (row 0 stays exactly 0)
__global__ __launch_bounds__(BLOCK) void convert_int8(
    const float4v* __restrict__ src, char4v* __restrict__ dst,
    const int* __restrict__ scale_bits)
{
    const float amax = __int_as_float(*scale_bits);
    const float inv  = (amax > 0.f) ? 127.0f / amax : 0.0f;
    const int i = blockIdx.x * BLOCK + threadIdx.x;
    if (i < N_VEC4) {
        float4v v = __builtin_nontemporal_load(&src[i]);
        char4v q;
        #pragma unroll
        for (int j = 0; j < 4; ++j) {
            float r = fminf(fmaxf(v[j] * inv, -127.f), 127.f);
            q[j] = (schar)(int)rintf(r);
        }
        dst[i] = q;
    }
}

// Agent-scope (sc0) byte gather: bypass L1 (random over 4 MB can never hit
// 32 KB L1 — skip the line-fill/evict machinery), but fill/hit L2 normally.
// NOT nt: nt marks lines evict-first in L2 too (round-5 regression, 1.5x).
#if __has_builtin(__builtin_amdgcn_raw_ptr_buffer_load_i8) && \
    __has_builtin(__builtin_amdgcn_make_buffer_rsrc)
#define HAVE_BUF_GATHER 1
__device__ __forceinline__ float gather_i8(__amdgcn_buffer_rsrc_t rsrc, unsigned byte_off) {
    return (float)(schar)__builtin_amdgcn_raw_ptr_buffer_load_i8(rsrc, byte_off, 0, /*aux=SC0*/1);
}
#else
#define HAVE_BUF_GATHER 0
#endif

// ---- k3: main — int8 table gather (4 MB, L2-resident) + wave-private LDS segment-sum
__global__ __launch_bounds__(BLOCK, 8) void wide_pool_i8(
    const int*   __restrict__ indexes,
    const int*   __restrict__ fields,
    const float* __restrict__ values,
    const schar* __restrict__ table8,
    const int*   __restrict__ scale_bits,
    float*       __restrict__ out)
{
    __shared__ float acc[ROWS_PER_BLK][NUM_SEGMENTS];

    const int tid  = threadIdx.x;
    const int wave = tid >> 6;
    const int lane = tid & 63;

    // wave-private accumulators; per-wave DS ops are in-order -> no barrier needed
    acc[wave][lane] = 0.0f;

    const long row  = (long)blockIdx.x * ROWS_PER_BLK + wave;
    const long base = row * SEQ;

    const int4v*   idx4 = (const int4v*)  (indexes + base);
    const int4v*   fld4 = (const int4v*)  (fields  + base);
    const float4v* val4 = (const float4v*)(values  + base);

    const bool second = (lane < 125 - 64);   // 500 = 125 vec4 per row

    // stage 1: non-temporal STREAM loads (zero reuse -> keep L2 for the table)
    int4v   ia = __builtin_nontemporal_load(&idx4[lane]);
    int4v   fa = __builtin_nontemporal_load(&fld4[lane]);
    float4v va = __builtin_nontemporal_load(&val4[lane]);
    int4v   ib = {0, 0, 0, 0};
    int4v   fb = {0, 0, 0, 0};
    float4v vb = {0.f, 0.f, 0.f, 0.f};
    if (second) {
        ib = __builtin_nontemporal_load(&idx4[lane + 64]);
        fb = __builtin_nontemporal_load(&fld4[lane + 64]);
        vb = __builtin_nontemporal_load(&val4[lane + 64]);
    }

    // stage 2: 8 independent gathers in flight. buffer_load_sbyte with sc0:
    // 32-bit voffset (no 64-bit addr chains), L1 bypass, normal L2 fill.
    // bucket 0 quantizes to exactly 0 -> no padding guard.
    float e[8];
#if HAVE_BUF_GATHER
    __amdgcn_buffer_rsrc_t rsrc =
        __builtin_amdgcn_make_buffer_rsrc((void*)table8, /*stride*/(short)0,
                                          /*num_records*/NUM_BUCKETS,
                                          /*flags*/0x00020000);
    #pragma unroll
    for (int j = 0; j < 4; ++j)
        e[j] = gather_i8(rsrc, (unsigned)ia[j] % NUM_BUCKETS);
    #pragma unroll
    for (int j = 0; j < 4; ++j)
        e[4 + j] = second ? gather_i8(rsrc, (unsigned)ib[j] % NUM_BUCKETS) : 0.0f;
#else
    #pragma unroll
    for (int j = 0; j < 4; ++j)
        e[j] = (float)table8[(unsigned)ia[j] % NUM_BUCKETS];
    #pragma unroll
    for (int j = 0; j < 4; ++j)
        e[4 + j] = second ? (float)table8[(unsigned)ib[j] % NUM_BUCKETS] : 0.0f;
#endif

    // stage 3: acc = sum(q * v); dequant once in the epilogue
    #pragma unroll
    for (int j = 0; j < 4; ++j)
        atomicAdd(&acc[wave][fa[j] & (NUM_SEGMENTS - 1)], e[j] * va[j]);
    if (second) {
        #pragma unroll
        for (int j = 0; j < 4; ++j)
            atomicAdd(&acc[wave][fb[j] & (NUM_SEGMENTS - 1)], e[4 + j] * vb[j]);
    }

    // epilogue: same wave reads back its own slots (in-order DS, no barrier)
    const float step = __int_as_float(*scale_bits) * (1.0f / 127.0f);
    if (lane >= 1)
        __builtin_nontemporal_store(acc[wave][lane] * step,
                                    &out[row * NUM_FIELDS + (lane - 1)]);
}

// ---- fallback: fp32 table direct (only if d_ws can't hold the int8 table)
__global__ __launch_bounds__(BLOCK, 8) void wide_pool_f32(
    const int*   __restrict__ indexes,
    const int*   __restrict__ fields,
    const float* __restrict__ values,
    const float* __restrict__ table,
    float*       __restrict__ out)
{
    __shared__ float acc[ROWS_PER_BLK][NUM_SEGMENTS];
    const int tid  = threadIdx.x;
    const int wave = tid >> 6;
    const int lane = tid & 63;
    acc[wave][lane] = 0.0f;
    __syncthreads();
    const long row  = (long)blockIdx.x * ROWS_PER_BLK + wave;
    const long base = row * SEQ;
    const int4v*   idx4 = (const int4v*)  (indexes + base);
    const int4v*   fld4 = (const int4v*)  (fields  + base);
    const float4v* val4 = (const float4v*)(values  + base);
    const bool second = (lane < 125 - 64);
    int4v   ia = __builtin_nontemporal_load(&idx4[lane]);
    int4v   fa = __builtin_nontemporal_load(&fld4[lane]);
    float4v va = __builtin_nontemporal_load(&val4[lane]);
    int4v   ib = {0,0,0,0}; int4v fb = {0,0,0,0}; float4v vb = {0.f,0.f,0.f,0.f};
    if (second) {
        ib = __builtin_nontemporal_load(&idx4[lane + 64]);
        fb = __builtin_nontemporal_load(&fld4[lane + 64]);
        vb = __builtin_nontemporal_load(&val4[lane + 64]);
    }
    float e[8];
    #pragma unroll
    for (int j = 0; j < 4; ++j) e[j] = table[(unsigned)ia[j] % NUM_BUCKETS];
    #pragma unroll
    for (int j = 0; j < 4; ++j) e[4 + j] = second ? table[(unsigned)ib[j] % NUM_BUCKETS] : 0.0f;
    #pragma unroll
    for (int j = 0; j < 4; ++j)
        atomicAdd(&acc[wave][fa[j] & (NUM_SEGMENTS - 1)], e[j] * va[j]);
    if (second) {
        #pragma unroll
        for (int j = 0; j < 4; ++j)
            atomicAdd(&acc[wave][fb[j] & (NUM_SEGMENTS - 1)], e[4 + j] * vb[j]);
    }
    __syncthreads();
    if (lane >= 1) out[row * NUM_FIELDS + (lane - 1)] = acc[wave][lane];
}

extern "C" void kernel_launch(void* const* d_in, const int* in_sizes, int n_in,
                              void* d_out, int out_size, void* d_ws, size_t ws_size,
                              hipStream_t stream) {
    const int*   indexes = (const int*)  d_in[0];
    const int*   fields  = (const int*)  d_in[1];
    const float* values  = (const float*)d_in[2];
    const float* table   = (const float*)d_in[3];
    float*       out     = (float*)      d_out;

    const size_t need = (size_t)NUM_BUCKETS + 4;   // 4 MB table + scale slot
    if (ws_size >= need) {
        schar* t8    = (schar*)d_ws;
        int*   sbits = (int*)((char*)d_ws + SCALE_OFF);
        hipMemsetAsync(sbits, 0, 4, stream);       // graph-legal init of absmax slot
        reduce_absmax<<<1024, BLOCK, 0, stream>>>((const float4v*)table, sbits);
        convert_int8<<<(N_VEC4 + BLOCK - 1) / BLOCK, BLOCK, 0, stream>>>(
            (const float4v*)table, (char4v*)t8, sbits);
        wide_pool_i8<<<BATCH / ROWS_PER_BLK, BLOCK, 0, stream>>>(
            indexes, fields, values, t8, sbits, out);
    } else {
        wide_pool_f32<<<BATCH / ROWS_PER_BLK, BLOCK, 0, stream>>>(
            indexes, fields, values, table, out);
    }
}

// Round 8
// 187.124 us; speedup vs baseline: 1.0377x; 1.0377x over previous
//
#include <hip/hip_runtime.h>

#define BATCH        16384
#define SEQ          500
#define NUM_BUCKETS  4000000
#define NUM_FIELDS   63
#define NUM_SEGMENTS 64
#define BLOCK        256
#define ROWS_PER_BLK 4          // one wave per batch row

typedef int         int4v   __attribute__((ext_vector_type(4)));
typedef float       float4v __attribute__((ext_vector_type(4)));
typedef signed char schar;
typedef schar       char4v  __attribute__((ext_vector_type(4)));

#define N_VEC4      (NUM_BUCKETS / 4)                 // 1,000,000 float4 groups
#define REG_SHIFT   10                                // region = 1024 buckets
#define NUM_REGIONS ((NUM_BUCKETS + 1023) >> REG_SHIFT)   // 3907

// d_ws layout: [0 .. 4M) int8 table | [4M ..) per-region scales (3907 floats)
#define SCALE_OFF NUM_BUCKETS

// ---- k1 (single pre-kernel): per-region absmax + int8 quantization.
// One block == one region of 1024 buckets (256 vec4s). Block-local reduce,
// no global atomics, no init kernel needed (every slot overwritten).
// Row 0 stays exactly 0 (0 quantizes to 0).
__global__ __launch_bounds__(BLOCK) void convert_int8_rs(
    const float4v* __restrict__ src,
    char4v*        __restrict__ dst,
    float*         __restrict__ scales)
{
    __shared__ float red[BLOCK / 64];
    const int tid = threadIdx.x;
    const int i   = blockIdx.x * BLOCK + tid;          // vec4 index
    const bool valid = (i < N_VEC4);

    float4v v = {0.f, 0.f, 0.f, 0.f};
    if (valid) v = __builtin_nontemporal_load(&src[i]);

    float m = 0.0f;
    #pragma unroll
    for (int j = 0; j < 4; ++j) m = fmaxf(m, fabsf(v[j]));
    #pragma unroll
    for (int off = 32; off >= 1; off >>= 1)
        m = fmaxf(m, __shfl_down(m, off, 64));
    if ((tid & 63) == 0) red[tid >> 6] = m;
    __syncthreads();
    const float bm  = fmaxf(fmaxf(red[0], red[1]), fmaxf(red[2], red[3]));
    const float inv = (bm > 0.f) ? 127.0f / bm : 0.0f;

    if (tid == 0) scales[blockIdx.x] = bm * (1.0f / 127.0f);   // dequant step

    if (valid) {
        char4v q;
        #pragma unroll
        for (int j = 0; j < 4; ++j)
            q[j] = (schar)(int)rintf(v[j] * inv);    // |v|<=bm -> no clamp needed
        dst[i] = q;
    }
}

// ---- k2: main — int8 table gather (4 MB, L2-resident; PLAIN cached loads —
// nt gathers poisoned L2 in r5; sc0 bypass was flat in r7) + per-region
// dequant from LDS + wave-private LDS segment-sum.
__global__ __launch_bounds__(BLOCK, 8) void wide_pool_i8(
    const int*   __restrict__ indexes,
    const int*   __restrict__ fields,
    const float* __restrict__ values,
    const schar* __restrict__ table8,
    const float* __restrict__ scales,
    float*       __restrict__ out)
{
    __shared__ float acc[ROWS_PER_BLK][NUM_SEGMENTS];   // 1 KB
    __shared__ float sc[NUM_REGIONS];                   // 15.6 KB -> 16.7 KB total, 8 blk/CU

    const int tid  = threadIdx.x;
    const int wave = tid >> 6;
    const int lane = tid & 63;

    // preload per-region scales (coalesced, L2-resident after first blocks)
    for (int i = tid; i < NUM_REGIONS; i += BLOCK) sc[i] = scales[i];
    acc[wave][lane] = 0.0f;
    __syncthreads();   // cross-wave: all waves need the full sc[] array

    const long row  = (long)blockIdx.x * ROWS_PER_BLK + wave;
    const long base = row * SEQ;

    const int4v*   idx4 = (const int4v*)  (indexes + base);
    const int4v*   fld4 = (const int4v*)  (fields  + base);
    const float4v* val4 = (const float4v*)(values  + base);

    const bool second = (lane < 125 - 64);   // 500 = 125 vec4 per row

    // stage 1: non-temporal STREAM loads (zero reuse -> keep L2 for the table)
    int4v   ia = __builtin_nontemporal_load(&idx4[lane]);
    int4v   fa = __builtin_nontemporal_load(&fld4[lane]);
    float4v va = __builtin_nontemporal_load(&val4[lane]);
    int4v   ib = {0, 0, 0, 0};
    int4v   fb = {0, 0, 0, 0};
    float4v vb = {0.f, 0.f, 0.f, 0.f};
    if (second) {
        ib = __builtin_nontemporal_load(&idx4[lane + 64]);
        fb = __builtin_nontemporal_load(&fld4[lane + 64]);
        vb = __builtin_nontemporal_load(&val4[lane + 64]);
    }

    // stage 2: buckets, then 8 independent gathers in flight; scale*value
    // (LDS read, independent of the in-flight gather) computed while waiting.
    unsigned ba[4], bb[4];
    #pragma unroll
    for (int j = 0; j < 4; ++j) ba[j] = (unsigned)ia[j] % NUM_BUCKETS;
    #pragma unroll
    for (int j = 0; j < 4; ++j) bb[j] = second ? (unsigned)ib[j] % NUM_BUCKETS : 0u;

    float e[8], sv[8];
    #pragma unroll
    for (int j = 0; j < 4; ++j) e[j] = (float)table8[ba[j]];
    #pragma unroll
    for (int j = 0; j < 4; ++j) e[4 + j] = second ? (float)table8[bb[j]] : 0.0f;
    #pragma unroll
    for (int j = 0; j < 4; ++j) sv[j] = sc[ba[j] >> REG_SHIFT] * va[j];
    #pragma unroll
    for (int j = 0; j < 4; ++j) sv[4 + j] = second ? sc[bb[j] >> REG_SHIFT] * vb[j] : 0.0f;

    // stage 3: segment-sum, already dequantized (q * step * v)
    #pragma unroll
    for (int j = 0; j < 4; ++j)
        atomicAdd(&acc[wave][fa[j] & (NUM_SEGMENTS - 1)], e[j] * sv[j]);
    if (second) {
        #pragma unroll
        for (int j = 0; j < 4; ++j)
            atomicAdd(&acc[wave][fb[j] & (NUM_SEGMENTS - 1)], e[4 + j] * sv[4 + j]);
    }

    // epilogue: same wave reads back its own slots (in-order DS, no barrier)
    if (lane >= 1)
        __builtin_nontemporal_store(acc[wave][lane],
                                    &out[row * NUM_FIELDS + (lane - 1)]);
}

// ---- fallback: fp32 table direct (only if d_ws can't hold table + scales)
__global__ __launch_bounds__(BLOCK, 8) void wide_pool_f32(
    const int*   __restrict__ indexes,
    const int*   __restrict__ fields,
    const float* __restrict__ values,
    const float* __restrict__ table,
    float*       __restrict__ out)
{
    __shared__ float acc[ROWS_PER_BLK][NUM_SEGMENTS];
    const int tid  = threadIdx.x;
    const int wave = tid >> 6;
    const int lane = tid & 63;
    acc[wave][lane] = 0.0f;
    __syncthreads();
    const long row  = (long)blockIdx.x * ROWS_PER_BLK + wave;
    const long base = row * SEQ;
    const int4v*   idx4 = (const int4v*)  (indexes + base);
    const int4v*   fld4 = (const int4v*)  (fields  + base);
    const float4v* val4 = (const float4v*)(values  + base);
    const bool second = (lane < 125 - 64);
    int4v   ia = __builtin_nontemporal_load(&idx4[lane]);
    int4v   fa = __builtin_nontemporal_load(&fld4[lane]);
    float4v va = __builtin_nontemporal_load(&val4[lane]);
    int4v   ib = {0,0,0,0}; int4v fb = {0,0,0,0}; float4v vb = {0.f,0.f,0.f,0.f};
    if (second) {
        ib = __builtin_nontemporal_load(&idx4[lane + 64]);
        fb = __builtin_nontemporal_load(&fld4[lane + 64]);
        vb = __builtin_nontemporal_load(&val4[lane + 64]);
    }
    float e[8];
    #pragma unroll
    for (int j = 0; j < 4; ++j) e[j] = table[(unsigned)ia[j] % NUM_BUCKETS];
    #pragma unroll
    for (int j = 0; j < 4; ++j) e[4 + j] = second ? table[(unsigned)ib[j] % NUM_BUCKETS] : 0.0f;
    #pragma unroll
    for (int j = 0; j < 4; ++j)
        atomicAdd(&acc[wave][fa[j] & (NUM_SEGMENTS - 1)], e[j] * va[j]);
    if (second) {
        #pragma unroll
        for (int j = 0; j < 4; ++j)
            atomicAdd(&acc[wave][fb[j] & (NUM_SEGMENTS - 1)], e[4 + j] * vb[j]);
    }
    __syncthreads();
    if (lane >= 1) out[row * NUM_FIELDS + (lane - 1)] = acc[wave][lane];
}

extern "C" void kernel_launch(void* const* d_in, const int* in_sizes, int n_in,
                              void* d_out, int out_size, void* d_ws, size_t ws_size,
                              hipStream_t stream) {
    const int*   indexes = (const int*)  d_in[0];
    const int*   fields  = (const int*)  d_in[1];
    const float* values  = (const float*)d_in[2];
    const float* table   = (const float*)d_in[3];
    float*       out     = (float*)      d_out;

    const size_t need = (size_t)NUM_BUCKETS + (size_t)NUM_REGIONS * 4;
    if (ws_size >= need) {
        schar* t8     = (schar*)d_ws;
        float* scales = (float*)((char*)d_ws + SCALE_OFF);
        convert_int8_rs<<<NUM_REGIONS, BLOCK, 0, stream>>>(
            (const float4v*)table, (char4v*)t8, scales);
        wide_pool_i8<<<BATCH / ROWS_PER_BLK, BLOCK, 0, stream>>>(
            indexes, fields, values, t8, scales, out);
    } else {
        wide_pool_f32<<<BATCH / ROWS_PER_BLK, BLOCK, 0, stream>>>(
            indexes, fields, values, table, out);
    }
}